// Round 18
// baseline (626.809 us; speedup 1.0000x reference)
//
#include <hip/hip_runtime.h>

// STGAN fused forward for MI355X. Shapes fixed per reference.
constexpr int cB = 4, cT = 24, cN = 10000, cF = 64, cE = 160000, cHID = 128, cK = 3;

typedef short s16x4 __attribute__((ext_vector_type(4)));
typedef short s16x8 __attribute__((ext_vector_type(8)));
typedef float f32x16 __attribute__((ext_vector_type(16)));

__device__ __forceinline__ unsigned short f2bf(float f) {   // RNE (one-time paths)
    union { float f; unsigned u; } c; c.f = f;
    unsigned u = c.u;
    return (unsigned short)((u + 0x7FFFu + ((u >> 16) & 1u)) >> 16);
}
__device__ __forceinline__ unsigned short f2bf_rtz(float f) {
    union { float f; unsigned u; } c; c.f = f;
    return (unsigned short)(c.u >> 16);
}
__device__ __forceinline__ unsigned asu(float f) {
    union { float f; unsigned u; } c; c.f = f; return c.u;
}

__device__ __forceinline__ float tanh_fast(float x) {
    float e = __expf(2.0f * x);
    return 1.0f - 2.0f * __builtin_amdgcn_rcpf(e + 1.0f);
}

// ---------- setup: zero cnt_in / cursor ----------
__global__ void k_zeroA(int* __restrict__ cnt_in, int* __restrict__ cursor) {
    int i = blockIdx.x * 256 + threadIdx.x;
    if (i < cN) { cnt_in[i] = 0; cursor[i] = 0; }
}

// ---------- CSR build; int64-vs-int32 detected per 256-edge block ----------
__global__ void k_count(const int* __restrict__ edges, int* __restrict__ cnt_in) {
    int e = blockIdx.x * 256 + threadIdx.x;
    int nz = __syncthreads_count(e < cE && edges[2 * e + 1] == 0);
    if (e < cE) {
        int m = (nz == 256) ? 2 : 1;
        atomicAdd(&cnt_in[edges[m * (cE + e)]], 1);
    }
}

// single-wave shfl scan (rowptr) + dinv fused; 16 elems/lane -> 10 iterations
__global__ void k_scan(const int* __restrict__ cnt_in, int* __restrict__ rowptr,
                       float* __restrict__ dinv) {
    int lane = threadIdx.x;   // 64 threads
    int carry = 0;
    for (int base = 0; base < cN; base += 1024) {
        int i0 = base + lane * 16;
        int v[16];
        int sum16 = 0;
        #pragma unroll
        for (int k = 0; k < 16; k++) {
            v[k] = (i0 + k < cN) ? cnt_in[i0 + k] : 0;
            sum16 += v[k];
        }
        int s = sum16;
        #pragma unroll
        for (int d = 1; d < 64; d <<= 1) {
            int u = __shfl_up(s, d, 64);
            if (lane >= d) s += u;
        }
        int pre = carry + s - sum16;   // exclusive prefix for this lane's 16
        #pragma unroll
        for (int k = 0; k < 16; k++) {
            if (i0 + k < cN) {
                rowptr[i0 + k] = pre;
                dinv[i0 + k] = rsqrtf((float)(v[k] + 1));
            }
            pre += v[k];
        }
        carry += __shfl(s, 63, 64);
    }
    if (lane == 0) rowptr[cN] = carry;
}

__global__ void k_fill(const int* __restrict__ edges, const int* __restrict__ rowptr,
                       int* __restrict__ cursor, int* __restrict__ csr_src) {
    int e = blockIdx.x * 256 + threadIdx.x;
    int nz = __syncthreads_count(e < cE && edges[2 * e + 1] == 0);
    if (e < cE) {
        int m = (nz == 256) ? 2 : 1;
        int r = edges[m * e];
        int c = edges[m * (cE + e)];
        int pos = atomicAdd(&cursor[c], 1);
        csr_src[rowptr[c] + pos] = r;
    }
}

// ---------- fused prep: blocks <hcB do hor_ctx; remaining 48 do W1 transpose ----------
__launch_bounds__(256)
__global__ void k_prep(const float* __restrict__ horizon, const float* __restrict__ W_hor,
                       const float* __restrict__ b_enc, float* __restrict__ hc,
                       const float* __restrict__ W1, unsigned short* __restrict__ W1T,
                       int hcB) {
    __shared__ float sLDS[64 * 65];   // 16.6 KB: hc uses 64*64; w1t uses [64][65]
    __shared__ float sm[4][64];
    const int tid = threadIdx.x;
    if ((int)blockIdx.x < hcB) {
        float* sW = sLDS;
        {
            const float4* src = (const float4*)W_hor;
            float4* dst = (float4*)sW;
            #pragma unroll
            for (int q = 0; q < 4; q++) dst[tid + q * 256] = src[tid + q * 256];
        }
        int g = tid & 63;
        int sub = tid >> 6;
        int pair = blockIdx.x * 4 + sub;          // b*N + n
        bool ok = pair < cB * cN;
        float m = 0.f;
        if (ok) {
            int b = pair / cN, n = pair % cN;
            const float* hp = horizon + ((size_t)(b * 6) * cN + n) * 64 + g;
            #pragma unroll
            for (int hh = 0; hh < 6; hh++) m += hp[(size_t)hh * cN * 64];
            m *= (1.0f / 6.0f);
        }
        sm[sub][g] = m;
        __syncthreads();
        if (!ok) return;
        float a = b_enc[g];
        #pragma unroll 8
        for (int f = 0; f < 64; f++) a = fmaf(sm[sub][f], sW[f * 64 + g], a);
        hc[(size_t)pair * 64 + g] = a;
    } else {
        float (*sT)[65] = (float(*)[65])sLDS;
        const int wb = blockIdx.x - hcB;          // 0..47
        const int t = wb % cT;                    // 24
        const int hx = (wb / cT) * 64;            // hid half
        const int gx = t * 64;
        #pragma unroll
        for (int r = 0; r < 4; r++) {
            int flat = tid + r * 256;             // float4 idx 0..1023
            int gp = flat >> 4, h4 = (flat & 15) * 4;
            float4 v = *(const float4*)&W1[(size_t)(gx + gp) * cHID + hx + h4];
            sT[h4 + 0][gp] = v.x; sT[h4 + 1][gp] = v.y;
            sT[h4 + 2][gp] = v.z; sT[h4 + 3][gp] = v.w;
        }
        __syncthreads();
        #pragma unroll
        for (int r = 0; r < 2; r++) {
            int flat = tid + r * 256;             // bf16x8 idx 0..511
            int h = flat >> 3, seg = flat & 7;
            s16x8 o;
            #pragma unroll
            for (int i = 0; i < 8; i++) o[i] = (short)f2bf(sT[h][seg * 8 + i]);
            *(s16x8*)&W1T[((size_t)t * cHID + hx + h) * 64 + seg * 8] = o;
        }
    }
}

// ---------- fused encode + MLP accumulate, bf16 MFMA, T-split z=2 ----------
// grid (313, B, 2); 2 waves / 32-node tile / 12-t half; LDS 12 KB.
// LB(128,4): cap VGPR at 128 (was 124 used under 256 cap) -> 4 waves/SIMD.
__launch_bounds__(128, 4)
__global__ void k_encode_mlp(const float* __restrict__ history,
                             const float* __restrict__ W_enc,
                             const float* __restrict__ hc,
                             const unsigned short* __restrict__ W1T,
                             const float* __restrict__ dinv,
                             float* __restrict__ accbuf,
                             float* __restrict__ y0) {
    __shared__ unsigned short sHist[2][32 * 64];   // [buf][node][f], swizzled, 8KB
    __shared__ unsigned short sXe[32 * 64];        // [node][g], swizzled, 4KB
    const int tid = threadIdx.x;    // 0..127
    const int lane = tid & 63;
    const int w = tid >> 6;         // 0..1
    const int l31 = lane & 31;
    const int lhi = lane >> 5;
    const int n0 = blockIdx.x * 32;
    const int b = blockIdx.y;
    const int zz = blockIdx.z;
    const int t0 = zz * (cT / 2), t1 = t0 + (cT / 2);
    const int nn = min(32, cN - n0);
    const int col = w * 32 + l31;   // encode output column (g)

    float4 r[4];
    auto RLOAD = [&](int t) {
        const float* hsrc = history + ((size_t)(b * cT + t) * cN + n0) * 64;
        #pragma unroll
        for (int q = 0; q < 4; q++) {
            int flat = tid + q * 128;       // float4 idx 0..511
            int node = flat >> 4, fq = flat & 15;
            r[q] = make_float4(0.f, 0.f, 0.f, 0.f);
            if (node < nn) r[q] = *(const float4*)(hsrc + node * 64 + fq * 4);
        }
    };
    auto SSTORE = [&](int buf) {
        #pragma unroll
        for (int q = 0; q < 4; q++) {
            int flat = tid + q * 128;
            int node = flat >> 4, fq = flat & 15;
            int2 p;
            p.x = (int)__builtin_amdgcn_perm(asu(r[q].y), asu(r[q].x), 0x07060302u);
            p.y = (int)__builtin_amdgcn_perm(asu(r[q].w), asu(r[q].z), 0x07060302u);
            int idx = (node * 64 + fq * 4) ^ ((node & 7) << 3);
            *(int2*)&sHist[buf][idx] = p;
        }
    };

    // W_enc B-fragments, register resident
    s16x8 wenc[4];
    #pragma unroll
    for (int ks = 0; ks < 4; ks++)
        #pragma unroll
        for (int i = 0; i < 8; i++)
            wenc[ks][i] = (short)f2bf(W_enc[(ks * 16 + lhi * 8 + i) * 64 + col]);

    // hc as loop-invariant C-init (precomputed); dinv loaded inline at last t
    float hcr[16];
    #pragma unroll
    for (int reg = 0; reg < 16; reg++) {
        int row = (reg & 3) + 8 * (reg >> 2) + 4 * lhi;
        hcr[reg] = (row < nn) ? hc[(size_t)(b * cN + n0 + row) * 64 + col] : 0.f;
    }

    f32x16 accm[2];
    #pragma unroll
    for (int ht = 0; ht < 2; ht++)
        #pragma unroll
        for (int rr = 0; rr < 16; rr++) accm[ht][rr] = 0.f;

    RLOAD(t0);
    SSTORE(0);
    int cur = 0;

    for (int t = t0; t < t1; t++) {
        const bool last = (t == cT - 1);
        const bool have_next = (t + 1 < t1);
        if (have_next) RLOAD(t + 1);   // issue a full iteration before consumption
        __syncthreads();   // sHist[cur] + sXe (prev readers) ready
        // encode MFMA: D[node][g], C-init = hcr
        f32x16 d;
        #pragma unroll
        for (int reg = 0; reg < 16; reg++) d[reg] = hcr[reg];
        {
            int base = l31 * 64 + lhi * 8;
            int sw = (l31 & 7) << 3;
            #pragma unroll
            for (int ks = 0; ks < 4; ks++) {
                s16x8 a = *(const s16x8*)&sHist[cur][(base + ks * 16) ^ sw];
                d = __builtin_amdgcn_mfma_f32_32x32x16_bf16(a, wenc[ks], d, 0, 0, 0);
            }
        }
        if (last) {
            #pragma unroll
            for (int reg = 0; reg < 16; reg++) {
                int row = (reg & 3) + 8 * (reg >> 2) + 4 * lhi;
                if (row < nn)
                    y0[(size_t)(n0 + row) * (cB * 64) + b * 64 + col] =
                        dinv[n0 + row] * tanh_fast(d[reg]);
            }
        } else {
            #pragma unroll
            for (int reg = 0; reg < 16; reg++) {
                int row = (reg & 3) + 8 * (reg >> 2) + 4 * lhi;
                int idx = (row * 64 + col) ^ ((row & 7) << 3);
                sXe[idx] = f2bf_rtz(tanh_fast(d[reg]));
            }
            __syncthreads();   // sXe visible
            // MLP: wave w owns hid rows w*64 .. w*64+63 (two 32-row tiles)
            int bbase = l31 * 64 + lhi * 8;
            int swB = (l31 & 7) << 3;
            #pragma unroll
            for (int ht = 0; ht < 2; ht++) {
                const unsigned short* wrow =
                    W1T + ((size_t)t * cHID + (w * 64 + ht * 32 + l31)) * 64 + lhi * 8;
                #pragma unroll
                for (int ks = 0; ks < 4; ks++) {
                    s16x8 aw = *(const s16x8*)(wrow + ks * 16);
                    s16x8 bx = *(const s16x8*)&sXe[(bbase + ks * 16) ^ swB];
                    accm[ht] = __builtin_amdgcn_mfma_f32_32x32x16_bf16(aw, bx, accm[ht], 0, 0, 0);
                }
            }
        }
        if (have_next) SSTORE(cur ^ 1);   // retire prefetch late: vmcnt fully covered
        cur ^= 1;
    }
    // store acc' partial (per z half): lane holds node = l31, hid rows per reg
    int node = l31;
    if (node < nn) {
        float* ap = accbuf + (size_t)zz * cB * cN * cHID + (size_t)(b * cN + n0 + node) * cHID;
        #pragma unroll
        for (int ht = 0; ht < 2; ht++) {
            #pragma unroll
            for (int q = 0; q < 4; q++) {
                int hid0 = w * 64 + ht * 32 + q * 8 + lhi * 4;
                float4 v = make_float4(accm[ht][q * 4 + 0], accm[ht][q * 4 + 1],
                                       accm[ht][q * 4 + 2], accm[ht][q * 4 + 3]);
                *(float4*)(ap + hid0) = v;
            }
        }
    }
}

// ---------- GCN step (fused gather + GEMM, commuted); 4 nodes / block ----------
__launch_bounds__(512)
__global__ void k_gstep(const int* __restrict__ rowptr, const int* __restrict__ csr_src,
                        const float* __restrict__ dinv, const float* __restrict__ yin,
                        const float* __restrict__ W_fc, const float* __restrict__ b_gcn,
                        float* __restrict__ yout) {
    __shared__ float sW[64 * 64];      // 16 KB
    __shared__ float sAgg[4][4][64];   // 4 KB
    const int tid = threadIdx.x;
    {
        const float4* src = (const float4*)W_fc;
        float4* dst = (float4*)sW;
        #pragma unroll
        for (int q = 0; q < 2; q++) dst[tid + q * 512] = src[tid + q * 512];
    }
    const int wv = tid >> 6;          // 0..7
    const int nl = wv >> 1;           // 0..3
    const int bp = wv & 1;            // batches {0,1} or {2,3}
    const int g = tid & 63;
    const int n = blockIdx.x * 4 + nl;
    if (n < cN) {
        const float* yn = yin + (size_t)n * 256 + bp * 128;
        float a0 = yn[g], a1 = yn[64 + g];
        int i = rowptr[n], end = rowptr[n + 1];
        for (; i + 4 <= end; i += 4) {
            int s0 = csr_src[i + 0], s1 = csr_src[i + 1];
            int s2 = csr_src[i + 2], s3 = csr_src[i + 3];
            const float* x0 = yin + (size_t)s0 * 256 + bp * 128;
            const float* x1 = yin + (size_t)s1 * 256 + bp * 128;
            const float* x2 = yin + (size_t)s2 * 256 + bp * 128;
            const float* x3 = yin + (size_t)s3 * 256 + bp * 128;
            float v00 = x0[g], v01 = x0[64 + g];
            float v10 = x1[g], v11 = x1[64 + g];
            float v20 = x2[g], v21 = x2[64 + g];
            float v30 = x3[g], v31 = x3[64 + g];
            a0 += (v00 + v10) + (v20 + v30);
            a1 += (v01 + v11) + (v21 + v31);
        }
        for (; i < end; i++) {
            int s = csr_src[i];
            const float* xs = yin + (size_t)s * 256 + bp * 128;
            a0 += xs[g]; a1 += xs[64 + g];
        }
        sAgg[nl][bp * 2 + 0][g] = a0;
        sAgg[nl][bp * 2 + 1][g] = a1;
    }
    __syncthreads();
    if (n >= cN) return;
    const float* g0 = sAgg[nl][bp * 2 + 0];
    const float* g1 = sAgg[nl][bp * 2 + 1];
    float o0 = 0.f, o1 = 0.f;
    #pragma unroll 8
    for (int f = 0; f < 64; f++) {
        float wv_ = sW[f * 64 + g];
        o0 = fmaf(g0[f], wv_, o0);
        o1 = fmaf(g1[f], wv_, o1);
    }
    float di = dinv[n], bg = b_gcn[g];
    float h0v = fmaf(di, o0, bg) * di;   // intermediate step: y = dinv*h
    float h1v = fmaf(di, o1, bg) * di;
    yout[(size_t)n * 256 + (bp * 2 + 0) * 64 + g] = h0v;
    yout[(size_t)n * 256 + (bp * 2 + 1) * 64 + g] = h1v;
}

// ---------- final GCN step + head fused ----------
__launch_bounds__(512)
__global__ void k_gstep_head(const int* __restrict__ rowptr, const int* __restrict__ csr_src,
                             const float* __restrict__ dinv, const float* __restrict__ yin,
                             const float* __restrict__ W_fc, const float* __restrict__ b_gcn,
                             const float* __restrict__ accbuf,
                             const float* __restrict__ W1, const float* __restrict__ b1,
                             const float* __restrict__ W2, const float* __restrict__ b2,
                             float* __restrict__ out) {
    __shared__ float sW[64 * 64];      // 16 KB
    __shared__ float sAgg[4][4][64];   // 4 KB (gather) -> reused as hfin store
    const int tid = threadIdx.x;
    {
        const float4* src = (const float4*)W_fc;
        float4* dst = (float4*)sW;
        #pragma unroll
        for (int q = 0; q < 2; q++) dst[tid + q * 512] = src[tid + q * 512];
    }
    const int wv = tid >> 6;          // 0..7
    const int nl = wv >> 1;           // 0..3
    const int bp = wv & 1;            // batches {0,1} or {2,3}
    const int g = tid & 63;
    const int n = blockIdx.x * 4 + nl;
    if (n < cN) {
        const float* yn = yin + (size_t)n * 256 + bp * 128;
        float a0 = yn[g], a1 = yn[64 + g];
        int i = rowptr[n], end = rowptr[n + 1];
        for (; i + 4 <= end; i += 4) {
            int s0 = csr_src[i + 0], s1 = csr_src[i + 1];
            int s2 = csr_src[i + 2], s3 = csr_src[i + 3];
            const float* x0 = yin + (size_t)s0 * 256 + bp * 128;
            const float* x1 = yin + (size_t)s1 * 256 + bp * 128;
            const float* x2 = yin + (size_t)s2 * 256 + bp * 128;
            const float* x3 = yin + (size_t)s3 * 256 + bp * 128;
            float v00 = x0[g], v01 = x0[64 + g];
            float v10 = x1[g], v11 = x1[64 + g];
            float v20 = x2[g], v21 = x2[64 + g];
            float v30 = x3[g], v31 = x3[64 + g];
            a0 += (v00 + v10) + (v20 + v30);
            a1 += (v01 + v11) + (v21 + v31);
        }
        for (; i < end; i++) {
            int s = csr_src[i];
            const float* xs = yin + (size_t)s * 256 + bp * 128;
            a0 += xs[g]; a1 += xs[64 + g];
        }
        sAgg[nl][bp * 2 + 0][g] = a0;
        sAgg[nl][bp * 2 + 1][g] = a1;
    }
    __syncthreads();
    float h0v = 0.f, h1v = 0.f;
    if (n < cN) {
        const float* g0 = sAgg[nl][bp * 2 + 0];
        const float* g1 = sAgg[nl][bp * 2 + 1];
        float o0 = 0.f, o1 = 0.f;
        #pragma unroll 8
        for (int f = 0; f < 64; f++) {
            float wv_ = sW[f * 64 + g];
            o0 = fmaf(g0[f], wv_, o0);
            o1 = fmaf(g1[f], wv_, o1);
        }
        float di = dinv[n], bg = b_gcn[g];
        h0v = fmaf(di, o0, bg);          // final step: raw h (no dinv fold)
        h1v = fmaf(di, o1, bg);
    }
    __syncthreads();   // all reads of sAgg(agg) done
    if (n < cN) {
        sAgg[nl][bp * 2 + 0][g] = h0v;
        sAgg[nl][bp * 2 + 1][g] = h1v;
    }
    __syncthreads();   // hfin visible
    if (n >= cN) return;
    // head for this wave's 2 pairs; lane covers j = g and g+64.
    const float* w1p = W1 + (size_t)(cT - 1) * 64 * cHID;
    float b1a = b1[g], b1b = b1[g + 64];
    float w2a = W2[g], w2b = W2[g + 64];
    #pragma unroll
    for (int pi = 0; pi < 2; pi++) {
        int bb = bp * 2 + pi;
        size_t pair = (size_t)bb * cN + n;
        const float* hrow = sAgg[nl][bb];
        const float* ac0 = accbuf + pair * cHID;
        const float* ac1 = accbuf + (size_t)cB * cN * cHID + pair * cHID;
        float a0 = ac0[g] + ac1[g] + b1a;
        float a1 = ac0[g + 64] + ac1[g + 64] + b1b;
        #pragma unroll 8
        for (int f = 0; f < 64; f++) {
            float hv = hrow[f];
            a0 = fmaf(hv, w1p[f * cHID + g], a0);
            a1 = fmaf(hv, w1p[f * cHID + g + 64], a1);
        }
        float s = fmaxf(a0, 0.f) * w2a + fmaxf(a1, 0.f) * w2b;
        #pragma unroll
        for (int d2 = 32; d2 > 0; d2 >>= 1) s += __shfl_down(s, d2, 64);
        if (g == 0) out[pair] = s + b2[0];
    }
}

extern "C" void kernel_launch(void* const* d_in, const int* in_sizes, int n_in,
                              void* d_out, int out_size, void* d_ws, size_t ws_size,
                              hipStream_t stream) {
    const float* history = (const float*)d_in[0];
    const float* horizon = (const float*)d_in[1];
    const int*   edges   = (const int*)d_in[2];
    const float* W_enc   = (const float*)d_in[3];
    const float* W_hor   = (const float*)d_in[4];
    const float* b_enc   = (const float*)d_in[5];
    const float* W_fc    = (const float*)d_in[6];
    const float* b_gcn   = (const float*)d_in[7];
    const float* W1      = (const float*)d_in[8];
    const float* b1      = (const float*)d_in[9];
    const float* W2      = (const float*)d_in[10];
    const float* b2      = (const float*)d_in[11];
    float* out = (float*)d_out;

    float* ws = (float*)d_ws;
    float* hc     = ws;                                   // B*N*64
    float* accbuf = hc + (size_t)cB * cN * 64;            // 2 * B*N*128 (z halves)
    float* yA     = accbuf + (size_t)2 * cB * cN * cHID;  // N*B*64 (n-major)
    float* yB     = yA + (size_t)cB * cN * 64;            // N*B*64 (n-major)
    float* dinv   = yB + (size_t)cB * cN * 64;            // N
    unsigned short* w1t = (unsigned short*)(dinv + cN);   // 24*128*64 bf16
    int*   cnt_in = (int*)(w1t + (size_t)cT * cHID * 64); // N
    int*   cursor = cnt_in + cN;                          // N
    int*   rowptr = cursor + cN;                          // N+1
    int*   csr_src= rowptr + cN + 1;                      // E

    const int hcB = (cB * cN + 3) / 4;   // 10000 hc blocks

    // CSR chain first (independent of encode; encode folds dinv)
    k_zeroA<<<(cN + 255) / 256, 256, 0, stream>>>(cnt_in, cursor);
    k_count<<<(cE + 255) / 256, 256, 0, stream>>>(edges, cnt_in);
    k_scan<<<1, 64, 0, stream>>>(cnt_in, rowptr, dinv);
    k_fill<<<(cE + 255) / 256, 256, 0, stream>>>(edges, rowptr, cursor, csr_src);

    k_prep<<<hcB + cT * 2, 256, 0, stream>>>(horizon, W_hor, b_enc, hc, W1, w1t, hcB);
    k_encode_mlp<<<dim3((cN + 31) / 32, cB, 2), 128, 0, stream>>>(history, W_enc, hc,
                                                                  w1t, dinv, accbuf, yA);

    // GCN: 2 intermediate fused gather+GEMM steps; final step fused with head
    k_gstep<<<(cN + 3) / 4, 512, 0, stream>>>(rowptr, csr_src, dinv, yA, W_fc, b_gcn, yB);
    k_gstep<<<(cN + 3) / 4, 512, 0, stream>>>(rowptr, csr_src, dinv, yB, W_fc, b_gcn, yA);
    k_gstep_head<<<(cN + 3) / 4, 512, 0, stream>>>(rowptr, csr_src, dinv, yA, W_fc, b_gcn,
                                                   accbuf, W1, b1, W2, b2, out);
}

// Round 19
// 314.967 us; speedup vs baseline: 1.9901x; 1.9901x over previous
//
#include <hip/hip_runtime.h>

// STGAN fused forward for MI355X. Shapes fixed per reference.
constexpr int cB = 4, cT = 24, cN = 10000, cF = 64, cE = 160000, cHID = 128, cK = 3;

typedef short s16x4 __attribute__((ext_vector_type(4)));
typedef short s16x8 __attribute__((ext_vector_type(8)));
typedef float f32x16 __attribute__((ext_vector_type(16)));

__device__ __forceinline__ unsigned short f2bf(float f) {   // RNE (one-time paths)
    union { float f; unsigned u; } c; c.f = f;
    unsigned u = c.u;
    return (unsigned short)((u + 0x7FFFu + ((u >> 16) & 1u)) >> 16);
}
__device__ __forceinline__ unsigned short f2bf_rtz(float f) {
    union { float f; unsigned u; } c; c.f = f;
    return (unsigned short)(c.u >> 16);
}
__device__ __forceinline__ unsigned asu(float f) {
    union { float f; unsigned u; } c; c.f = f; return c.u;
}

__device__ __forceinline__ float tanh_fast(float x) {
    float e = __expf(2.0f * x);
    return 1.0f - 2.0f * __builtin_amdgcn_rcpf(e + 1.0f);
}

// ---------- setup: zero cnt_in / cursor ----------
__global__ void k_zeroA(int* __restrict__ cnt_in, int* __restrict__ cursor) {
    int i = blockIdx.x * 256 + threadIdx.x;
    if (i < cN) { cnt_in[i] = 0; cursor[i] = 0; }
}

// ---------- CSR build; int64-vs-int32 detected per 256-edge block ----------
__global__ void k_count(const int* __restrict__ edges, int* __restrict__ cnt_in) {
    int e = blockIdx.x * 256 + threadIdx.x;
    int nz = __syncthreads_count(e < cE && edges[2 * e + 1] == 0);
    if (e < cE) {
        int m = (nz == 256) ? 2 : 1;
        atomicAdd(&cnt_in[edges[m * (cE + e)]], 1);
    }
}

// single-wave shfl scan (rowptr) + dinv fused; 16 elems/lane -> 10 iterations
__global__ void k_scan(const int* __restrict__ cnt_in, int* __restrict__ rowptr,
                       float* __restrict__ dinv) {
    int lane = threadIdx.x;   // 64 threads
    int carry = 0;
    for (int base = 0; base < cN; base += 1024) {
        int i0 = base + lane * 16;
        int v[16];
        int sum16 = 0;
        #pragma unroll
        for (int k = 0; k < 16; k++) {
            v[k] = (i0 + k < cN) ? cnt_in[i0 + k] : 0;
            sum16 += v[k];
        }
        int s = sum16;
        #pragma unroll
        for (int d = 1; d < 64; d <<= 1) {
            int u = __shfl_up(s, d, 64);
            if (lane >= d) s += u;
        }
        int pre = carry + s - sum16;   // exclusive prefix for this lane's 16
        #pragma unroll
        for (int k = 0; k < 16; k++) {
            if (i0 + k < cN) {
                rowptr[i0 + k] = pre;
                dinv[i0 + k] = rsqrtf((float)(v[k] + 1));
            }
            pre += v[k];
        }
        carry += __shfl(s, 63, 64);
    }
    if (lane == 0) rowptr[cN] = carry;
}

__global__ void k_fill(const int* __restrict__ edges, const int* __restrict__ rowptr,
                       int* __restrict__ cursor, int* __restrict__ csr_src) {
    int e = blockIdx.x * 256 + threadIdx.x;
    int nz = __syncthreads_count(e < cE && edges[2 * e + 1] == 0);
    if (e < cE) {
        int m = (nz == 256) ? 2 : 1;
        int r = edges[m * e];
        int c = edges[m * (cE + e)];
        int pos = atomicAdd(&cursor[c], 1);
        csr_src[rowptr[c] + pos] = r;
    }
}

// ---------- fused prep: blocks <hcB do hor_ctx; remaining 48 do W1 transpose ----------
__launch_bounds__(256)
__global__ void k_prep(const float* __restrict__ horizon, const float* __restrict__ W_hor,
                       const float* __restrict__ b_enc, float* __restrict__ hc,
                       const float* __restrict__ W1, unsigned short* __restrict__ W1T,
                       int hcB) {
    __shared__ float sLDS[64 * 65];   // 16.6 KB: hc uses 64*64; w1t uses [64][65]
    __shared__ float sm[4][64];
    const int tid = threadIdx.x;
    if ((int)blockIdx.x < hcB) {
        float* sW = sLDS;
        {
            const float4* src = (const float4*)W_hor;
            float4* dst = (float4*)sW;
            #pragma unroll
            for (int q = 0; q < 4; q++) dst[tid + q * 256] = src[tid + q * 256];
        }
        int g = tid & 63;
        int sub = tid >> 6;
        int pair = blockIdx.x * 4 + sub;          // b*N + n
        bool ok = pair < cB * cN;
        float m = 0.f;
        if (ok) {
            int b = pair / cN, n = pair % cN;
            const float* hp = horizon + ((size_t)(b * 6) * cN + n) * 64 + g;
            #pragma unroll
            for (int hh = 0; hh < 6; hh++) m += hp[(size_t)hh * cN * 64];
            m *= (1.0f / 6.0f);
        }
        sm[sub][g] = m;
        __syncthreads();
        if (!ok) return;
        float a = b_enc[g];
        #pragma unroll 8
        for (int f = 0; f < 64; f++) a = fmaf(sm[sub][f], sW[f * 64 + g], a);
        hc[(size_t)pair * 64 + g] = a;
    } else {
        float (*sT)[65] = (float(*)[65])sLDS;
        const int wb = blockIdx.x - hcB;          // 0..47
        const int t = wb % cT;                    // 24
        const int hx = (wb / cT) * 64;            // hid half
        const int gx = t * 64;
        #pragma unroll
        for (int r = 0; r < 4; r++) {
            int flat = tid + r * 256;             // float4 idx 0..1023
            int gp = flat >> 4, h4 = (flat & 15) * 4;
            float4 v = *(const float4*)&W1[(size_t)(gx + gp) * cHID + hx + h4];
            sT[h4 + 0][gp] = v.x; sT[h4 + 1][gp] = v.y;
            sT[h4 + 2][gp] = v.z; sT[h4 + 3][gp] = v.w;
        }
        __syncthreads();
        #pragma unroll
        for (int r = 0; r < 2; r++) {
            int flat = tid + r * 256;             // bf16x8 idx 0..511
            int h = flat >> 3, seg = flat & 7;
            s16x8 o;
            #pragma unroll
            for (int i = 0; i < 8; i++) o[i] = (short)f2bf(sT[h][seg * 8 + i]);
            *(s16x8*)&W1T[((size_t)t * cHID + hx + h) * 64 + seg * 8] = o;
        }
    }
}

// ---------- fused encode + MLP accumulate, bf16 MFMA, T-split z=2 (R17 proven) ----------
__launch_bounds__(128, 2)
__global__ void k_encode_mlp(const float* __restrict__ history,
                             const float* __restrict__ W_enc,
                             const float* __restrict__ hc,
                             const unsigned short* __restrict__ W1T,
                             const float* __restrict__ dinv,
                             float* __restrict__ accbuf,
                             float* __restrict__ y0) {
    __shared__ unsigned short sHist[2][32 * 64];   // [buf][node][f], swizzled, 8KB
    __shared__ unsigned short sXe[32 * 64];        // [node][g], swizzled, 4KB
    const int tid = threadIdx.x;    // 0..127
    const int lane = tid & 63;
    const int w = tid >> 6;         // 0..1
    const int l31 = lane & 31;
    const int lhi = lane >> 5;
    const int n0 = blockIdx.x * 32;
    const int b = blockIdx.y;
    const int zz = blockIdx.z;
    const int t0 = zz * (cT / 2), t1 = t0 + (cT / 2);
    const int nn = min(32, cN - n0);
    const int col = w * 32 + l31;   // encode output column (g)

    float4 r[4];
    auto RLOAD = [&](int t) {
        const float* hsrc = history + ((size_t)(b * cT + t) * cN + n0) * 64;
        #pragma unroll
        for (int q = 0; q < 4; q++) {
            int flat = tid + q * 128;       // float4 idx 0..511
            int node = flat >> 4, fq = flat & 15;
            r[q] = make_float4(0.f, 0.f, 0.f, 0.f);
            if (node < nn) r[q] = *(const float4*)(hsrc + node * 64 + fq * 4);
        }
    };
    auto SSTORE = [&](int buf) {
        #pragma unroll
        for (int q = 0; q < 4; q++) {
            int flat = tid + q * 128;
            int node = flat >> 4, fq = flat & 15;
            int2 p;
            p.x = (int)__builtin_amdgcn_perm(asu(r[q].y), asu(r[q].x), 0x07060302u);
            p.y = (int)__builtin_amdgcn_perm(asu(r[q].w), asu(r[q].z), 0x07060302u);
            int idx = (node * 64 + fq * 4) ^ ((node & 7) << 3);
            *(int2*)&sHist[buf][idx] = p;
        }
    };

    // W_enc B-fragments, register resident
    s16x8 wenc[4];
    #pragma unroll
    for (int ks = 0; ks < 4; ks++)
        #pragma unroll
        for (int i = 0; i < 8; i++)
            wenc[ks][i] = (short)f2bf(W_enc[(ks * 16 + lhi * 8 + i) * 64 + col]);

    // hc as loop-invariant C-init (precomputed); dinv per output row (z=1 store)
    float hcr[16];
    float dvr[16];
    #pragma unroll
    for (int reg = 0; reg < 16; reg++) {
        int row = (reg & 3) + 8 * (reg >> 2) + 4 * lhi;
        bool okr = row < nn;
        hcr[reg] = okr ? hc[(size_t)(b * cN + n0 + row) * 64 + col] : 0.f;
        dvr[reg] = okr ? dinv[n0 + row] : 0.f;
    }

    f32x16 accm[2];
    #pragma unroll
    for (int ht = 0; ht < 2; ht++)
        #pragma unroll
        for (int rr = 0; rr < 16; rr++) accm[ht][rr] = 0.f;

    RLOAD(t0);
    SSTORE(0);
    int cur = 0;

    for (int t = t0; t < t1; t++) {
        const bool last = (t == cT - 1);
        const bool have_next = (t + 1 < t1);
        if (have_next) RLOAD(t + 1);   // issue a full iteration before consumption
        __syncthreads();   // sHist[cur] + sXe (prev readers) ready
        // encode MFMA: D[node][g], C-init = hcr
        f32x16 d;
        #pragma unroll
        for (int reg = 0; reg < 16; reg++) d[reg] = hcr[reg];
        {
            int base = l31 * 64 + lhi * 8;
            int sw = (l31 & 7) << 3;
            #pragma unroll
            for (int ks = 0; ks < 4; ks++) {
                s16x8 a = *(const s16x8*)&sHist[cur][(base + ks * 16) ^ sw];
                d = __builtin_amdgcn_mfma_f32_32x32x16_bf16(a, wenc[ks], d, 0, 0, 0);
            }
        }
        if (last) {
            #pragma unroll
            for (int reg = 0; reg < 16; reg++) {
                int row = (reg & 3) + 8 * (reg >> 2) + 4 * lhi;
                if (row < nn)
                    y0[(size_t)(n0 + row) * (cB * 64) + b * 64 + col] =
                        dvr[reg] * tanh_fast(d[reg]);
            }
        } else {
            #pragma unroll
            for (int reg = 0; reg < 16; reg++) {
                int row = (reg & 3) + 8 * (reg >> 2) + 4 * lhi;
                int idx = (row * 64 + col) ^ ((row & 7) << 3);
                sXe[idx] = f2bf_rtz(tanh_fast(d[reg]));
            }
            __syncthreads();   // sXe visible
            // MLP: wave w owns hid rows w*64 .. w*64+63 (two 32-row tiles)
            int bbase = l31 * 64 + lhi * 8;
            int swB = (l31 & 7) << 3;
            #pragma unroll
            for (int ht = 0; ht < 2; ht++) {
                const unsigned short* wrow =
                    W1T + ((size_t)t * cHID + (w * 64 + ht * 32 + l31)) * 64 + lhi * 8;
                #pragma unroll
                for (int ks = 0; ks < 4; ks++) {
                    s16x8 aw = *(const s16x8*)(wrow + ks * 16);
                    s16x8 bx = *(const s16x8*)&sXe[(bbase + ks * 16) ^ swB];
                    accm[ht] = __builtin_amdgcn_mfma_f32_32x32x16_bf16(aw, bx, accm[ht], 0, 0, 0);
                }
            }
        }
        if (have_next) SSTORE(cur ^ 1);   // retire prefetch late: vmcnt fully covered
        cur ^= 1;
    }
    // store acc' partial (per z half): lane holds node = l31, hid rows per reg
    int node = l31;
    if (node < nn) {
        float* ap = accbuf + (size_t)zz * cB * cN * cHID + (size_t)(b * cN + n0 + node) * cHID;
        #pragma unroll
        for (int ht = 0; ht < 2; ht++) {
            #pragma unroll
            for (int q = 0; q < 4; q++) {
                int hid0 = w * 64 + ht * 32 + q * 8 + lhi * 4;
                float4 v = make_float4(accm[ht][q * 4 + 0], accm[ht][q * 4 + 1],
                                       accm[ht][q * 4 + 2], accm[ht][q * 4 + 3]);
                *(float4*)(ap + hid0) = v;
            }
        }
    }
}

// ---------- GCN step (fused gather + GEMM, commuted); 4 nodes / block ----------
__launch_bounds__(512)
__global__ void k_gstep(const int* __restrict__ rowptr, const int* __restrict__ csr_src,
                        const float* __restrict__ dinv, const float* __restrict__ yin,
                        const float* __restrict__ W_fc, const float* __restrict__ b_gcn,
                        float* __restrict__ yout) {
    __shared__ float sW[64 * 64];      // 16 KB
    __shared__ float sAgg[4][4][64];   // 4 KB
    const int tid = threadIdx.x;
    {
        const float4* src = (const float4*)W_fc;
        float4* dst = (float4*)sW;
        #pragma unroll
        for (int q = 0; q < 2; q++) dst[tid + q * 512] = src[tid + q * 512];
    }
    const int wv = tid >> 6;          // 0..7
    const int nl = wv >> 1;           // 0..3
    const int bp = wv & 1;            // batches {0,1} or {2,3}
    const int g = tid & 63;
    const int n = blockIdx.x * 4 + nl;
    if (n < cN) {
        const float* yn = yin + (size_t)n * 256 + bp * 128;
        float a0 = yn[g], a1 = yn[64 + g];
        int i = rowptr[n], end = rowptr[n + 1];
        for (; i + 4 <= end; i += 4) {
            int s0 = csr_src[i + 0], s1 = csr_src[i + 1];
            int s2 = csr_src[i + 2], s3 = csr_src[i + 3];
            const float* x0 = yin + (size_t)s0 * 256 + bp * 128;
            const float* x1 = yin + (size_t)s1 * 256 + bp * 128;
            const float* x2 = yin + (size_t)s2 * 256 + bp * 128;
            const float* x3 = yin + (size_t)s3 * 256 + bp * 128;
            float v00 = x0[g], v01 = x0[64 + g];
            float v10 = x1[g], v11 = x1[64 + g];
            float v20 = x2[g], v21 = x2[64 + g];
            float v30 = x3[g], v31 = x3[64 + g];
            a0 += (v00 + v10) + (v20 + v30);
            a1 += (v01 + v11) + (v21 + v31);
        }
        for (; i < end; i++) {
            int s = csr_src[i];
            const float* xs = yin + (size_t)s * 256 + bp * 128;
            a0 += xs[g]; a1 += xs[64 + g];
        }
        sAgg[nl][bp * 2 + 0][g] = a0;
        sAgg[nl][bp * 2 + 1][g] = a1;
    }
    __syncthreads();
    if (n >= cN) return;
    const float* g0 = sAgg[nl][bp * 2 + 0];
    const float* g1 = sAgg[nl][bp * 2 + 1];
    float o0 = 0.f, o1 = 0.f;
    #pragma unroll 8
    for (int f = 0; f < 64; f++) {
        float wv_ = sW[f * 64 + g];
        o0 = fmaf(g0[f], wv_, o0);
        o1 = fmaf(g1[f], wv_, o1);
    }
    float di = dinv[n], bg = b_gcn[g];
    float h0v = fmaf(di, o0, bg) * di;   // intermediate step: y = dinv*h
    float h1v = fmaf(di, o1, bg) * di;
    yout[(size_t)n * 256 + (bp * 2 + 0) * 64 + g] = h0v;
    yout[(size_t)n * 256 + (bp * 2 + 1) * 64 + g] = h1v;
}

// ---------- final GCN step + head fused ----------
__launch_bounds__(512)
__global__ void k_gstep_head(const int* __restrict__ rowptr, const int* __restrict__ csr_src,
                             const float* __restrict__ dinv, const float* __restrict__ yin,
                             const float* __restrict__ W_fc, const float* __restrict__ b_gcn,
                             const float* __restrict__ accbuf,
                             const float* __restrict__ W1, const float* __restrict__ b1,
                             const float* __restrict__ W2, const float* __restrict__ b2,
                             float* __restrict__ out) {
    __shared__ float sW[64 * 64];      // 16 KB
    __shared__ float sAgg[4][4][64];   // 4 KB (gather) -> reused as hfin store
    const int tid = threadIdx.x;
    {
        const float4* src = (const float4*)W_fc;
        float4* dst = (float4*)sW;
        #pragma unroll
        for (int q = 0; q < 2; q++) dst[tid + q * 512] = src[tid + q * 512];
    }
    const int wv = tid >> 6;          // 0..7
    const int nl = wv >> 1;           // 0..3
    const int bp = wv & 1;            // batches {0,1} or {2,3}
    const int g = tid & 63;
    const int n = blockIdx.x * 4 + nl;
    if (n < cN) {
        const float* yn = yin + (size_t)n * 256 + bp * 128;
        float a0 = yn[g], a1 = yn[64 + g];
        int i = rowptr[n], end = rowptr[n + 1];
        for (; i + 4 <= end; i += 4) {
            int s0 = csr_src[i + 0], s1 = csr_src[i + 1];
            int s2 = csr_src[i + 2], s3 = csr_src[i + 3];
            const float* x0 = yin + (size_t)s0 * 256 + bp * 128;
            const float* x1 = yin + (size_t)s1 * 256 + bp * 128;
            const float* x2 = yin + (size_t)s2 * 256 + bp * 128;
            const float* x3 = yin + (size_t)s3 * 256 + bp * 128;
            float v00 = x0[g], v01 = x0[64 + g];
            float v10 = x1[g], v11 = x1[64 + g];
            float v20 = x2[g], v21 = x2[64 + g];
            float v30 = x3[g], v31 = x3[64 + g];
            a0 += (v00 + v10) + (v20 + v30);
            a1 += (v01 + v11) + (v21 + v31);
        }
        for (; i < end; i++) {
            int s = csr_src[i];
            const float* xs = yin + (size_t)s * 256 + bp * 128;
            a0 += xs[g]; a1 += xs[64 + g];
        }
        sAgg[nl][bp * 2 + 0][g] = a0;
        sAgg[nl][bp * 2 + 1][g] = a1;
    }
    __syncthreads();
    float h0v = 0.f, h1v = 0.f;
    if (n < cN) {
        const float* g0 = sAgg[nl][bp * 2 + 0];
        const float* g1 = sAgg[nl][bp * 2 + 1];
        float o0 = 0.f, o1 = 0.f;
        #pragma unroll 8
        for (int f = 0; f < 64; f++) {
            float wv_ = sW[f * 64 + g];
            o0 = fmaf(g0[f], wv_, o0);
            o1 = fmaf(g1[f], wv_, o1);
        }
        float di = dinv[n], bg = b_gcn[g];
        h0v = fmaf(di, o0, bg);          // final step: raw h (no dinv fold)
        h1v = fmaf(di, o1, bg);
    }
    __syncthreads();   // all reads of sAgg(agg) done
    if (n < cN) {
        sAgg[nl][bp * 2 + 0][g] = h0v;
        sAgg[nl][bp * 2 + 1][g] = h1v;
    }
    __syncthreads();   // hfin visible
    if (n >= cN) return;
    // head for this wave's 2 pairs; lane covers j = g and g+64.
    const float* w1p = W1 + (size_t)(cT - 1) * 64 * cHID;
    float b1a = b1[g], b1b = b1[g + 64];
    float w2a = W2[g], w2b = W2[g + 64];
    #pragma unroll
    for (int pi = 0; pi < 2; pi++) {
        int bb = bp * 2 + pi;
        size_t pair = (size_t)bb * cN + n;
        const float* hrow = sAgg[nl][bb];
        const float* ac0 = accbuf + pair * cHID;
        const float* ac1 = accbuf + (size_t)cB * cN * cHID + pair * cHID;
        float a0 = ac0[g] + ac1[g] + b1a;
        float a1 = ac0[g + 64] + ac1[g + 64] + b1b;
        #pragma unroll 8
        for (int f = 0; f < 64; f++) {
            float hv = hrow[f];
            a0 = fmaf(hv, w1p[f * cHID + g], a0);
            a1 = fmaf(hv, w1p[f * cHID + g + 64], a1);
        }
        float s = fmaxf(a0, 0.f) * w2a + fmaxf(a1, 0.f) * w2b;
        #pragma unroll
        for (int d2 = 32; d2 > 0; d2 >>= 1) s += __shfl_down(s, d2, 64);
        if (g == 0) out[pair] = s + b2[0];
    }
}

extern "C" void kernel_launch(void* const* d_in, const int* in_sizes, int n_in,
                              void* d_out, int out_size, void* d_ws, size_t ws_size,
                              hipStream_t stream) {
    const float* history = (const float*)d_in[0];
    const float* horizon = (const float*)d_in[1];
    const int*   edges   = (const int*)d_in[2];
    const float* W_enc   = (const float*)d_in[3];
    const float* W_hor   = (const float*)d_in[4];
    const float* b_enc   = (const float*)d_in[5];
    const float* W_fc    = (const float*)d_in[6];
    const float* b_gcn   = (const float*)d_in[7];
    const float* W1      = (const float*)d_in[8];
    const float* b1      = (const float*)d_in[9];
    const float* W2      = (const float*)d_in[10];
    const float* b2      = (const float*)d_in[11];
    float* out = (float*)d_out;

    float* ws = (float*)d_ws;
    float* hc     = ws;                                   // B*N*64
    float* accbuf = hc + (size_t)cB * cN * 64;            // 2 * B*N*128 (z halves)
    float* yA     = accbuf + (size_t)2 * cB * cN * cHID;  // N*B*64 (n-major)
    float* yB     = yA + (size_t)cB * cN * 64;            // N*B*64 (n-major)
    float* dinv   = yB + (size_t)cB * cN * 64;            // N
    unsigned short* w1t = (unsigned short*)(dinv + cN);   // 24*128*64 bf16
    int*   cnt_in = (int*)(w1t + (size_t)cT * cHID * 64); // N
    int*   cursor = cnt_in + cN;                          // N
    int*   rowptr = cursor + cN;                          // N+1
    int*   csr_src= rowptr + cN + 1;                      // E

    const int hcB = (cB * cN + 3) / 4;   // 10000 hc blocks

    // CSR chain first (independent of encode; encode folds dinv)
    k_zeroA<<<(cN + 255) / 256, 256, 0, stream>>>(cnt_in, cursor);
    k_count<<<(cE + 255) / 256, 256, 0, stream>>>(edges, cnt_in);
    k_scan<<<1, 64, 0, stream>>>(cnt_in, rowptr, dinv);
    k_fill<<<(cE + 255) / 256, 256, 0, stream>>>(edges, rowptr, cursor, csr_src);

    k_prep<<<hcB + cT * 2, 256, 0, stream>>>(horizon, W_hor, b_enc, hc, W1, w1t, hcB);
    k_encode_mlp<<<dim3((cN + 31) / 32, cB, 2), 128, 0, stream>>>(history, W_enc, hc,
                                                                  w1t, dinv, accbuf, yA);

    // GCN: 2 intermediate fused gather+GEMM steps; final step fused with head
    k_gstep<<<(cN + 3) / 4, 512, 0, stream>>>(rowptr, csr_src, dinv, yA, W_fc, b_gcn, yB);
    k_gstep<<<(cN + 3) / 4, 512, 0, stream>>>(rowptr, csr_src, dinv, yB, W_fc, b_gcn, yA);
    k_gstep_head<<<(cN + 3) / 4, 512, 0, stream>>>(rowptr, csr_src, dinv, yA, W_fc, b_gcn,
                                                   accbuf, W1, b1, W2, b2, out);
}